// Round 13
// baseline (65142.407 us; speedup 1.0000x reference)
//
#include <hip/hip_runtime.h>

// ---------------- problem constants ----------------
#define NN      16384      // total nodes
#define TSTEPS  32
#define SG      256        // graphs
#define NE      262144

// ---------------- workspace layout (float offsets) ----------------
#define OFF_ENC_MEM   0u
#define OFF_ENC_SPK   2097152u
#define OFF_C1_MEM    4194304u
#define OFF_C1_SPK    6291456u     // == xl [256][8192]
#define OFF_LH        8388608u
#define OFF_LC        8519680u
#define OFF_H1_MEM    8650752u
#define OFF_H1_SPK    8716288u
#define OFF_H2_MEM    8781824u
#define OFF_H2_SPK    8782848u
#define OFF_H2_SUM    8783872u
#define ZERO_FLOATS   8784896u     // everything below here zeroed each launch
#define OFF_BASES     8784896u
#define OFF_COMB      9833472u
#define OFF_GATES     10357760u    // 256 x 2048
#define OFF_THH       10882048u    // 256 x 2048 (reuses old partials space)
#define OFF_DINV      23464960u
#define OFF_COLW      23481344u
#define FLOAT_END     23743488u
// int region (offsets from ibase)
#define IOFF_DEG      0
#define IOFF_FILL     16384
#define IOFF_ROWPTR   32768
#define IOFF_EID      49153        // reused as spike bitmask msk[8192][8] after preprocessing
#define IOFF_COL      311297
#define INT_COUNT     573441

// ---------------- graph preprocessing ----------------
__global__ void k_deg(const int* __restrict__ ei, int* __restrict__ deg) {
  int e = blockIdx.x * 256 + threadIdx.x;
  if (e < NE) atomicAdd(&deg[ei[NE + e]], 1);
}

__global__ void k_dinv(const int* __restrict__ deg, float* __restrict__ dinv) {
  int n = blockIdx.x * 256 + threadIdx.x;
  if (n < NN) dinv[n] = __fdiv_rn(1.0f, __fsqrt_rn((float)(deg[n] + 1)));  // +1 self-loop
}

__global__ void k_scan(const int* __restrict__ deg, int* __restrict__ rowp) {
  __shared__ int sdata[1024];
  int tid = threadIdx.x;
  int base = tid * 16;
  int loc[16];
  int sum = 0;
  #pragma unroll
  for (int i = 0; i < 16; ++i) { loc[i] = sum; sum += deg[base + i]; }
  sdata[tid] = sum;
  __syncthreads();
  for (int off = 1; off < 1024; off <<= 1) {
    int v = 0;
    if (tid >= off) v = sdata[tid - off];
    __syncthreads();
    sdata[tid] += v;
    __syncthreads();
  }
  int excl = (tid == 0) ? 0 : sdata[tid - 1];
  #pragma unroll
  for (int i = 0; i < 16; ++i) rowp[base + i] = excl + loc[i];
  if (tid == 1023) rowp[NN] = sdata[1023];
}

__global__ void k_scatter(const int* __restrict__ ei, const int* __restrict__ rowp,
                          int* __restrict__ fill, int* __restrict__ eid) {
  int e = blockIdx.x * 256 + threadIdx.x;
  if (e >= NE) return;
  int d = ei[NE + e];
  int pos = rowp[d] + atomicAdd(&fill[d], 1);
  eid[pos] = e;
}

// sort each adjacency list by EDGE ID (unique keys) -> summation order == scatter-add order
__global__ void k_sortadj(const int* __restrict__ rowp, int* __restrict__ eid,
                          const int* __restrict__ ei, const float* __restrict__ dinv,
                          int* __restrict__ col, float* __restrict__ colw) {
  int d = blockIdx.x * 256 + threadIdx.x;
  if (d >= NN) return;
  int r0 = rowp[d], r1 = rowp[d + 1];
  for (int i = r0 + 1; i < r1; ++i) {
    int key = eid[i];
    int j = i - 1;
    while (j >= r0 && eid[j] > key) { eid[j + 1] = eid[j]; --j; }
    eid[j + 1] = key;
  }
  for (int i = r0; i < r1; ++i) {
    int s = ei[eid[i]];
    col[i] = s;
    colw[i] = dinv[s];
  }
}

// ---------------- per-timestep kernels ----------------
// FUSED: enc LIF (in-block, 64 nodes) -> bases/comb GEMMs. 512 threads.
// Also zeroes the spike bitmask for this timestep (256 words/block).
__global__ __launch_bounds__(512) void k_bases_comb(
    const float* __restrict__ x, const float* __restrict__ encW, const float* __restrict__ encB,
    float* __restrict__ enc_mem, float* __restrict__ enc_spk,
    const float* __restrict__ basesW, const float* __restrict__ basesB,
    const float* __restrict__ combW, const float* __restrict__ combB,
    float* __restrict__ bases, float* __restrict__ comb,
    unsigned int* __restrict__ msk, int t) {
  __shared__ float xs[64][8];      // staged inputs for this block's 64 nodes
  __shared__ float sp[64 * 129];   // [node][j], pad 129 -> (n+j)%32 banks
  __shared__ float ob[64 * 65];    // bases out [node][ch], pad 65
  __shared__ float oc[64 * 33];    // comb out [node][ch], pad 33
  const int tid = threadIdx.x;
  const int nb = blockIdx.x * 64;
  if (tid < 256) msk[blockIdx.x * 256 + tid] = 0u;   // 256 blocks x 256 = 65536 words
  {
    int n = tid >> 3, c = tid & 7;
    xs[n][c] = x[(size_t)(nb + n) * 256 + (size_t)c * 32 + t];
  }
  __syncthreads();
  #pragma unroll 4
  for (int k = 0; k < 16; ++k) {
    int idx = k * 512 + tid;
    int n = idx >> 7, j = idx & 127;
    int gidx = nb * 128 + idx;
    float dot = 0.f;
    #pragma unroll
    for (int c = 0; c < 8; ++c) dot = __fmaf_rn(xs[n][c], encW[c * 128 + j], dot);
    float m = enc_mem[gidx], s = enc_spk[gidx];
    float nm = __fadd_rn(__fadd_rn(__fmul_rn(__fmul_rn(m, 0.2f), __fsub_rn(1.f, s)), dot), encB[j]);
    enc_mem[gidx] = nm;
    float spk = nm > 0.5f ? 1.f : 0.f;
    enc_spk[gidx] = spk;
    sp[n * 129 + j] = spk;
  }
  __syncthreads();
  const int lane = tid & 63;
  const int w = tid >> 6;
  const float* spn = sp + lane * 129;
  if (w < 4) {
    const int ch0 = w * 16;
    const float* Wp = basesW + ch0;
    float acc[16];
    #pragma unroll
    for (int c = 0; c < 16; ++c) acc[c] = 0.f;
    for (int j = 0; j < 128; ++j) {
      const float s = spn[j];
      const float* wr = Wp + j * 64;
      #pragma unroll
      for (int c = 0; c < 16; ++c) acc[c] = __fmaf_rn(s, wr[c], acc[c]);
    }
    #pragma unroll
    for (int c = 0; c < 16; ++c) ob[lane * 65 + ch0 + c] = acc[c];
  } else {
    const int ch0 = (w - 4) * 8;
    const float* Wp = combW + ch0;
    float acc[8];
    #pragma unroll
    for (int c = 0; c < 8; ++c) acc[c] = 0.f;
    for (int j = 0; j < 128; ++j) {
      const float s = spn[j];
      const float* wr = Wp + j * 32;
      #pragma unroll
      for (int c = 0; c < 8; ++c) acc[c] = __fmaf_rn(s, wr[c], acc[c]);
    }
    #pragma unroll
    for (int c = 0; c < 8; ++c) oc[lane * 33 + ch0 + c] = acc[c];
  }
  __syncthreads();
  #pragma unroll
  for (int r = 0; r < 8; ++r) {
    int idx = r * 512 + tid;
    int n = idx >> 6, ch = idx & 63;
    bases[(size_t)(nb + n) * 64 + ch] = __fadd_rn(ob[n * 65 + ch], basesB[ch]);
  }
  #pragma unroll
  for (int r = 0; r < 4; ++r) {
    int idx = r * 512 + tid;
    int n = idx >> 5, ch = idx & 31;
    comb[(size_t)(nb + n) * 32 + ch] = __fadd_rn(oc[n * 33 + ch], combB[ch]);
  }
}

// fused: symnorm aggregation -> einsum -> conv LIF -> c1 spike (x4 unrolled gather)
// + publish spike bits into msk[k_xl][sg] via atomicOr (OR is order-independent).
__global__ __launch_bounds__(256) void k_aggconv(
    const float* __restrict__ bases, const float* __restrict__ comb,
    const float* __restrict__ dinv, const int* __restrict__ rowp,
    const int* __restrict__ col, const float* __restrict__ colw,
    const float* __restrict__ convB,
    float* __restrict__ c1_mem, float* __restrict__ c1_spk,
    unsigned int* __restrict__ msk) {
  __shared__ float aggl[4][64];
  __shared__ float combl[4][32];
  int w = threadIdx.x >> 6;
  int m = threadIdx.x & 63;
  int d = blockIdx.x * 4 + w;
  float dd = dinv[d];
  int r0 = rowp[d], r1 = rowp[d + 1];
  float acc = 0.f;
  int r = r0;
  for (; r + 4 <= r1; r += 4) {
    const int s0 = col[r], s1 = col[r + 1], s2 = col[r + 2], s3 = col[r + 3];
    const float w0 = colw[r], w1 = colw[r + 1], w2 = colw[r + 2], w3 = colw[r + 3];
    const float b0 = bases[(size_t)s0 * 64 + m];
    const float b1 = bases[(size_t)s1 * 64 + m];
    const float b2 = bases[(size_t)s2 * 64 + m];
    const float b3 = bases[(size_t)s3 * 64 + m];
    acc = __fadd_rn(acc, __fmul_rn(__fmul_rn(w0, dd), b0));
    acc = __fadd_rn(acc, __fmul_rn(__fmul_rn(w1, dd), b1));
    acc = __fadd_rn(acc, __fmul_rn(__fmul_rn(w2, dd), b2));
    acc = __fadd_rn(acc, __fmul_rn(__fmul_rn(w3, dd), b3));
  }
  for (; r < r1; ++r) {
    int s = col[r];
    float ew  = __fmul_rn(colw[r], dd);
    float upd = __fmul_rn(ew, bases[(size_t)s * 64 + m]);
    acc = __fadd_rn(acc, upd);
  }
  {
    float ew  = __fmul_rn(dd, dd);
    float upd = __fmul_rn(ew, bases[(size_t)d * 64 + m]);
    acc = __fadd_rn(acc, upd);
  }
  aggl[w][m] = acc;
  if (m < 32) combl[w][m] = comb[(size_t)d * 32 + m];
  __syncthreads();
  const int sg8 = d >> 6;             // graph index 0..255
  const int kbase = (d & 63) * 128;   // xl k-offset of this node
  #pragma unroll
  for (int half = 0; half < 2; ++half) {
    int j = m + half * 64;
    int h = j >> 4, f = j & 15;
    float cv = 0.f;
    #pragma unroll
    for (int b = 0; b < 4; ++b)
      cv = __fadd_rn(cv, __fmul_rn(combl[w][h * 4 + b], aggl[w][b * 16 + f]));
    cv = __fadd_rn(cv, convB[j]);
    int idx = d * 128 + j;
    float cm = c1_mem[idx], cs = c1_spk[idx];
    float nm = __fadd_rn(__fmul_rn(__fmul_rn(cm, 0.2f), __fsub_rn(1.f, cs)), cv);
    c1_mem[idx] = nm;
    float spk = nm > 0.5f ? 1.f : 0.f;
    c1_spk[idx] = spk;
    if (spk != 0.f)
      atomicOr(&msk[(size_t)(kbase + j) * 8 + (sg8 >> 5)], 1u << (sg8 & 31));
  }
}

// dense lh @ Whh: computes thh = p22 + p23 directly (2-phase dbuf GEMM).
// Each phase's per-output chain: fma ascending k (kt asc, kk asc) == verified
// dense panel chain; thh = fadd(acc22, acc23) == verified k_combine thh.
__global__ __launch_bounds__(512) void k_gpanel_hh(
    const float* __restrict__ lh, const float* __restrict__ Whh,
    float* __restrict__ thh) {
  __shared__ __align__(16) float Ast[2][16][132];
  __shared__ __align__(16) float Bs[2][16][132];
  const int tid = threadIdx.x;
  const int tx = tid & 31;
  const int ty = tid >> 5;
  const int n0 = blockIdx.x * 128;
  const int m0 = blockIdx.y * 128;
  const int lda = 512;

  const int arow = tid >> 2;
  const int acol = (tid & 3) * 4;
  const int brow = tid >> 5;
  const int bcol = (tid & 31) * 4;

  float acc[8][4];
  float a22[8][4];
  float4 va, vb;

  #pragma unroll 1
  for (int ph = 0; ph < 2; ++ph) {
    const int k0 = ph ? 384 : 0;
    const int klen = ph ? 128 : 384;
    const int nkt = klen >> 4;
    #pragma unroll
    for (int i = 0; i < 8; ++i)
      #pragma unroll
      for (int j = 0; j < 4; ++j) acc[i][j] = 0.f;
    __syncthreads();   // previous phase fully done with LDS
    va = *(const float4*)(lh + (size_t)(m0 + arow) * lda + k0 + acol);
    vb = *(const float4*)(Whh + (size_t)(k0 + brow) * 2048 + n0 + bcol);
    Ast[0][acol + 0][arow] = va.x; Ast[0][acol + 1][arow] = va.y;
    Ast[0][acol + 2][arow] = va.z; Ast[0][acol + 3][arow] = va.w;
    *(float4*)&Bs[0][brow][bcol] = vb;
    __syncthreads();
    for (int kt = 0; kt < nkt; ++kt) {
      const int cur = kt & 1;
      const bool more = (kt + 1 < nkt);
      if (more) {
        const int kb = k0 + ((kt + 1) << 4);
        va = *(const float4*)(lh + (size_t)(m0 + arow) * lda + kb + acol);
        vb = *(const float4*)(Whh + (size_t)(kb + brow) * 2048 + n0 + bcol);
      }
      #pragma unroll
      for (int kk = 0; kk < 16; ++kk) {
        const float4 a0 = *(const float4*)&Ast[cur][kk][ty * 8];
        const float4 a1 = *(const float4*)&Ast[cur][kk][ty * 8 + 4];
        const float4 b0 = *(const float4*)&Bs[cur][kk][tx * 4];
        const float av[8] = {a0.x, a0.y, a0.z, a0.w, a1.x, a1.y, a1.z, a1.w};
        const float bv[4] = {b0.x, b0.y, b0.z, b0.w};
        #pragma unroll
        for (int i = 0; i < 8; ++i)
          #pragma unroll
          for (int j = 0; j < 4; ++j)
            acc[i][j] = __fmaf_rn(av[i], bv[j], acc[i][j]);
      }
      if (more) {
        const int nxt = cur ^ 1;
        Ast[nxt][acol + 0][arow] = va.x; Ast[nxt][acol + 1][arow] = va.y;
        Ast[nxt][acol + 2][arow] = va.z; Ast[nxt][acol + 3][arow] = va.w;
        *(float4*)&Bs[nxt][brow][bcol] = vb;
        __syncthreads();
      }
    }
    if (ph == 0) {
      #pragma unroll
      for (int i = 0; i < 8; ++i)
        #pragma unroll
        for (int j = 0; j < 4; ++j) a22[i][j] = acc[i][j];
    }
  }

  float* dst = thh + (size_t)m0 * 2048 + n0;
  #pragma unroll
  for (int i = 0; i < 8; ++i) {
    const int mr = ty * 8 + i;
    *(float4*)(dst + (size_t)mr * 2048 + tx * 4) = make_float4(
        __fadd_rn(a22[i][0], acc[i][0]), __fadd_rn(a22[i][1], acc[i][1]),
        __fadd_rn(a22[i][2], acc[i][2]), __fadd_rn(a22[i][3], acc[i][3]));
  }
}

// k-major broadcast gates: 64 blocks (one per 32-col slice), walk k=0..8191
// once. Per wave: one 32-graph mask word (wave-uniform LDS broadcast read);
// word==0 -> skip (71% of k's at ~1% density). On hit: load Wih[k][slice]
// (128B line, shared by all waves), fadd into per-thread-owned pz cells.
// Panel folds (21 in-loop at k=384z + 1 final) accumulate pz into tih regs
// (static indices) -> exact verified 22-fold left-to-right chain. Writes
// FINAL gates = ((tih + bih) + thh) + bhh (== verified k_combine epilogue).
__global__ __launch_bounds__(512) void k_gates_bcast(
    const float* __restrict__ Wih, const unsigned int* __restrict__ msk,
    const float* __restrict__ thh, const float* __restrict__ bih,
    const float* __restrict__ bhh, float* __restrict__ gates) {
  __shared__ float pz[256 * 32];        // 32 KB (per-thread-owned cells)
  __shared__ unsigned int mlds[512 * 8];  // 16 KB mask chunk [kk][word]
  const int tid = threadIdx.x;
  const int lane = tid & 63, wv = tid >> 6;      // wv = mask word (32 graphs)
  const int colc = lane & 31, half = lane >> 5;  // half = 16-bit half of word
  const int cl = blockIdx.x * 32;
  const int sbase = wv * 32 + half * 16;

  float tih_[16];
  #pragma unroll
  for (int i = 0; i < 16; ++i) tih_[i] = 0.f;
  #pragma unroll
  for (int i = 0; i < 16; ++i) pz[(sbase + i) * 32 + colc] = 0.f;

  const float* __restrict__ Wb = Wih + cl + colc;
  int nextfold = 384;
  int k = 0;
  for (int c = 0; c < 16; ++c) {
    __syncthreads();                     // done with previous mask chunk
    #pragma unroll
    for (int i = 0; i < 8; ++i) mlds[i * 512 + tid] = msk[c * 4096 + i * 512 + tid];
    __syncthreads();
    for (int kk = 0; kk < 512; ++kk, ++k) {
      if (k == nextfold) {               // wave-uniform (k uniform); 21 in-loop folds
        #pragma unroll
        for (int i = 0; i < 16; ++i) {
          const int ci = (sbase + i) * 32 + colc;
          tih_[i] = __fadd_rn(tih_[i], pz[ci]);
          pz[ci] = 0.f;
        }
        nextfold += 384;
      }
      const unsigned int w32 = mlds[kk * 8 + wv];   // wave-uniform broadcast
      if (w32 == 0u) continue;                      // wave-uniform skip
      const float wval = Wb[(size_t)k * 2048];
      unsigned int mh = (w32 >> (half * 16)) & 0xffffu;
      while (mh) {
        const int b = __ffs(mh) - 1; mh &= mh - 1;
        const int ci = (sbase + b) * 32 + colc;
        pz[ci] = __fadd_rn(pz[ci], wval);
      }
    }
  }
  // final fold (panel 21) -> 22 folds total, matching the verified chain
  #pragma unroll
  for (int i = 0; i < 16; ++i)
    tih_[i] = __fadd_rn(tih_[i], pz[(sbase + i) * 32 + colc]);

  const int colg = cl + colc;
  const float bi = bih[colg];
  const float bh = bhh[colg];
  #pragma unroll
  for (int i = 0; i < 16; ++i) {
    const int s = sbase + i;
    const float th = thh[(size_t)s * 2048 + colg];
    gates[(size_t)s * 2048 + colg] =
        __fadd_rn(__fadd_rn(__fadd_rn(tih_[i], bi), th), bh);
  }
}

// fused: gate spikes -> LSTM cell -> fc1 LIF -> fc2 LIF -> h2 accum. 512 threads.
__global__ __launch_bounds__(512) void k_cell(
    const float* __restrict__ gates,
    float* __restrict__ lc, float* __restrict__ lh,
    const float* __restrict__ fc1W, const float* __restrict__ fc1b,
    const float* __restrict__ fc2W, const float* __restrict__ fc2b,
    float* __restrict__ h1_mem, float* __restrict__ h1_spk,
    float* __restrict__ h2_mem, float* __restrict__ h2_spk, float* __restrict__ h2_sum) {
  __shared__ float lhl[512];
  __shared__ float a1buf[256];
  __shared__ float sp1l[256];
  const int s = blockIdx.x;
  const int tid = threadIdx.x;
  {
    const int h = tid;
    const float giv = gates[(size_t)s * 2048 + h];
    const float gfv = gates[(size_t)s * 2048 + 512 + h];
    const float ggv = gates[(size_t)s * 2048 + 1024 + h];
    const float gov = gates[(size_t)s * 2048 + 1536 + h];
    const float iv = giv > 0.f ? 1.f : 0.f;
    const float fv = gfv > 0.f ? 1.f : 0.f;
    const float gv = ggv > 0.f ? 1.f : 0.f;
    const float ov = gov > 0.f ? 1.f : 0.f;
    const int li = s * 512 + h;
    const float lcv = __fadd_rn(__fmul_rn(fv, lc[li]), __fmul_rn(iv, gv));
    lc[li] = lcv;
    const float lhv = __fmul_rn(lcv, ov);
    lh[li] = lhv;
    lhl[h] = lhv;
  }
  __syncthreads();
  float a0 = 0.f;
  if (tid < 256) {
    const int p = tid;
    #pragma unroll 8
    for (int q = 0; q < 384; ++q) a0 = __fmaf_rn(lhl[q], fc1W[q * 256 + p], a0);
  } else {
    const int p = tid - 256;
    float a1 = 0.f;
    #pragma unroll 8
    for (int q = 384; q < 512; ++q) a1 = __fmaf_rn(lhl[q], fc1W[q * 256 + p], a1);
    a1buf[p] = a1;
  }
  __syncthreads();
  if (tid < 256) {
    const int p = tid;
    const float dot1 = __fadd_rn(a0, a1buf[p]);
    const int i1 = s * 256 + p;
    const float m1 = h1_mem[i1], s1o = h1_spk[i1];
    const float nm1 = __fadd_rn(__fadd_rn(__fmul_rn(__fmul_rn(m1, 0.2f), __fsub_rn(1.f, s1o)), dot1), fc1b[p]);
    h1_mem[i1] = nm1;
    const float sp1 = nm1 > 0.5f ? 1.f : 0.f;
    h1_spk[i1] = sp1;
    sp1l[p] = sp1;
  }
  __syncthreads();
  if (tid < 4) {
    const int p = tid;
    float acc = 0.f;
    for (int q = 0; q < 256; ++q) acc = __fmaf_rn(sp1l[q], fc2W[q * 4 + p], acc);
    const int i2 = s * 4 + p;
    const float m2 = h2_mem[i2], s2o = h2_spk[i2];
    const float nm2 = __fadd_rn(__fadd_rn(__fmul_rn(__fmul_rn(m2, 0.2f), __fsub_rn(1.f, s2o)), acc), fc2b[p]);
    h2_mem[i2] = nm2;
    const float sp2 = nm2 > 0.5f ? 1.f : 0.f;
    h2_spk[i2] = sp2;
    h2_sum[i2] = __fadd_rn(h2_sum[i2], sp2);
  }
}

__global__ void k_out(const float* __restrict__ h2_sum, float* __restrict__ out) {
  int i = blockIdx.x * 256 + threadIdx.x;
  if (i < SG * 4) out[i] = __fmul_rn(h2_sum[i], 0.03125f);
}

// ---------------- launch ----------------
extern "C" void kernel_launch(void* const* d_in, const int* in_sizes, int n_in,
                              void* d_out, int out_size, void* d_ws, size_t ws_size,
                              hipStream_t stream) {
  const float* x      = (const float*)d_in[0];
  const int*   ei     = (const int*)  d_in[1];
  const float* encW   = (const float*)d_in[2];
  const float* encB   = (const float*)d_in[3];
  const float* basesW = (const float*)d_in[4];
  const float* basesB = (const float*)d_in[5];
  const float* combW  = (const float*)d_in[6];
  const float* combB  = (const float*)d_in[7];
  const float* convB  = (const float*)d_in[8];
  const float* Wih    = (const float*)d_in[9];
  const float* Whh    = (const float*)d_in[10];
  const float* bih    = (const float*)d_in[11];
  const float* bhh    = (const float*)d_in[12];
  const float* fc1W   = (const float*)d_in[13];
  const float* fc1b   = (const float*)d_in[14];
  const float* fc2W   = (const float*)d_in[15];
  const float* fc2b   = (const float*)d_in[16];

  float* ws = (float*)d_ws;
  float* enc_mem = ws + OFF_ENC_MEM;
  float* enc_spk = ws + OFF_ENC_SPK;
  float* c1_mem  = ws + OFF_C1_MEM;
  float* c1_spk  = ws + OFF_C1_SPK;   // xl
  float* lhp     = ws + OFF_LH;
  float* lcp     = ws + OFF_LC;
  float* h1_mem  = ws + OFF_H1_MEM;
  float* h1_spk  = ws + OFF_H1_SPK;
  float* h2_mem  = ws + OFF_H2_MEM;
  float* h2_spk  = ws + OFF_H2_SPK;
  float* h2_sum  = ws + OFF_H2_SUM;
  float* bases   = ws + OFF_BASES;
  float* comb    = ws + OFF_COMB;
  float* gates   = ws + OFF_GATES;
  float* thhp    = ws + OFF_THH;
  float* dinv    = ws + OFF_DINV;
  float* colw    = ws + OFF_COLW;
  int* ibase = (int*)((char*)d_ws + (size_t)FLOAT_END * 4);
  int* deg  = ibase + IOFF_DEG;
  int* fill = ibase + IOFF_FILL;
  int* rowp = ibase + IOFF_ROWPTR;
  int* eid  = ibase + IOFF_EID;
  int* col  = ibase + IOFF_COL;
  unsigned int* msk = (unsigned int*)(ibase + IOFF_EID);  // reuse after preprocessing

  hipMemsetAsync(ws, 0, (size_t)ZERO_FLOATS * 4, stream);
  hipMemsetAsync(ibase, 0, 32768 * 4, stream);

  k_deg    <<<NE / 256, 256, 0, stream>>>(ei, deg);
  k_dinv   <<<NN / 256, 256, 0, stream>>>(deg, dinv);
  k_scan   <<<1, 1024, 0, stream>>>(deg, rowp);
  k_scatter<<<NE / 256, 256, 0, stream>>>(ei, rowp, fill, eid);
  k_sortadj<<<NN / 256, 256, 0, stream>>>(rowp, eid, ei, dinv, col, colw);

  for (int t = 0; t < TSTEPS; ++t) {
    k_bases_comb<<<NN / 64, 512, 0, stream>>>(x, encW, encB, enc_mem, enc_spk,
                                              basesW, basesB, combW, combB, bases, comb, msk, t);
    k_aggconv   <<<NN / 4, 256, 0, stream>>>(bases, comb, dinv, rowp, col, colw, convB,
                                             c1_mem, c1_spk, msk);
    k_gpanel_hh <<<dim3(16, 2), 512, 0, stream>>>(lhp, Whh, thhp);
    k_gates_bcast<<<64, 512, 0, stream>>>(Wih, msk, thhp, bih, bhh, gates);
    k_cell      <<<SG, 512, 0, stream>>>(gates, lcp, lhp, fc1W, fc1b, fc2W, fc2b,
                                         h1_mem, h1_spk, h2_mem, h2_spk, h2_sum);
  }
  k_out<<<4, 256, 0, stream>>>(h2_sum, (float*)d_out);
}

// Round 14
// 6513.581 us; speedup vs baseline: 10.0010x; 10.0010x over previous
//
#include <hip/hip_runtime.h>

// ---------------- problem constants ----------------
#define NN      16384      // total nodes
#define TSTEPS  32
#define SG      256        // graphs
#define NE      262144

// ---------------- workspace layout (float offsets) ----------------
#define OFF_ENC_MEM   0u
#define OFF_ENC_SPK   2097152u
#define OFF_C1_MEM    4194304u
#define OFF_C1_SPK    6291456u     // == xl [256][8192]
#define OFF_LH        8388608u
#define OFF_LC        8519680u
#define OFF_H1_MEM    8650752u
#define OFF_H1_SPK    8716288u
#define OFF_H2_MEM    8781824u
#define OFF_H2_SPK    8782848u
#define OFF_H2_SUM    8783872u
#define ZERO_FLOATS   8784896u     // everything below here zeroed each launch
#define OFF_BASES     8784896u
#define OFF_COMB      9833472u
#define OFF_GATES     10357760u    // 256 x 2048
#define OFF_DINV      23464960u
#define OFF_COLW      23481344u
#define FLOAT_END     23743488u
// int region (offsets from ibase)
#define IOFF_DEG      0
#define IOFF_FILL     16384
#define IOFF_ROWPTR   32768
#define IOFF_EID      49153
#define IOFF_COL      311297
#define INT_COUNT     573441

// ---------------- graph preprocessing ----------------
__global__ void k_deg(const int* __restrict__ ei, int* __restrict__ deg) {
  int e = blockIdx.x * 256 + threadIdx.x;
  if (e < NE) atomicAdd(&deg[ei[NE + e]], 1);
}

__global__ void k_dinv(const int* __restrict__ deg, float* __restrict__ dinv) {
  int n = blockIdx.x * 256 + threadIdx.x;
  if (n < NN) dinv[n] = __fdiv_rn(1.0f, __fsqrt_rn((float)(deg[n] + 1)));  // +1 self-loop
}

__global__ void k_scan(const int* __restrict__ deg, int* __restrict__ rowp) {
  __shared__ int sdata[1024];
  int tid = threadIdx.x;
  int base = tid * 16;
  int loc[16];
  int sum = 0;
  #pragma unroll
  for (int i = 0; i < 16; ++i) { loc[i] = sum; sum += deg[base + i]; }
  sdata[tid] = sum;
  __syncthreads();
  for (int off = 1; off < 1024; off <<= 1) {
    int v = 0;
    if (tid >= off) v = sdata[tid - off];
    __syncthreads();
    sdata[tid] += v;
    __syncthreads();
  }
  int excl = (tid == 0) ? 0 : sdata[tid - 1];
  #pragma unroll
  for (int i = 0; i < 16; ++i) rowp[base + i] = excl + loc[i];
  if (tid == 1023) rowp[NN] = sdata[1023];
}

__global__ void k_scatter(const int* __restrict__ ei, const int* __restrict__ rowp,
                          int* __restrict__ fill, int* __restrict__ eid) {
  int e = blockIdx.x * 256 + threadIdx.x;
  if (e >= NE) return;
  int d = ei[NE + e];
  int pos = rowp[d] + atomicAdd(&fill[d], 1);
  eid[pos] = e;
}

// sort each adjacency list by EDGE ID (unique keys) -> summation order == scatter-add order
__global__ void k_sortadj(const int* __restrict__ rowp, int* __restrict__ eid,
                          const int* __restrict__ ei, const float* __restrict__ dinv,
                          int* __restrict__ col, float* __restrict__ colw) {
  int d = blockIdx.x * 256 + threadIdx.x;
  if (d >= NN) return;
  int r0 = rowp[d], r1 = rowp[d + 1];
  for (int i = r0 + 1; i < r1; ++i) {
    int key = eid[i];
    int j = i - 1;
    while (j >= r0 && eid[j] > key) { eid[j + 1] = eid[j]; --j; }
    eid[j + 1] = key;
  }
  for (int i = r0; i < r1; ++i) {
    int s = ei[eid[i]];
    col[i] = s;
    colw[i] = dinv[s];
  }
}

// ---------------- per-timestep kernels ----------------
// FUSED: enc LIF (in-block, 64 nodes) -> bases/comb GEMMs. 512 threads.
__global__ __launch_bounds__(512) void k_bases_comb(
    const float* __restrict__ x, const float* __restrict__ encW, const float* __restrict__ encB,
    float* __restrict__ enc_mem, float* __restrict__ enc_spk,
    const float* __restrict__ basesW, const float* __restrict__ basesB,
    const float* __restrict__ combW, const float* __restrict__ combB,
    float* __restrict__ bases, float* __restrict__ comb, int t) {
  __shared__ float xs[64][8];      // staged inputs for this block's 64 nodes
  __shared__ float sp[64 * 129];   // [node][j], pad 129 -> (n+j)%32 banks
  __shared__ float ob[64 * 65];    // bases out [node][ch], pad 65
  __shared__ float oc[64 * 33];    // comb out [node][ch], pad 33
  const int tid = threadIdx.x;
  const int nb = blockIdx.x * 64;
  {
    int n = tid >> 3, c = tid & 7;
    xs[n][c] = x[(size_t)(nb + n) * 256 + (size_t)c * 32 + t];
  }
  __syncthreads();
  #pragma unroll 4
  for (int k = 0; k < 16; ++k) {
    int idx = k * 512 + tid;
    int n = idx >> 7, j = idx & 127;
    int gidx = nb * 128 + idx;
    float dot = 0.f;
    #pragma unroll
    for (int c = 0; c < 8; ++c) dot = __fmaf_rn(xs[n][c], encW[c * 128 + j], dot);
    float m = enc_mem[gidx], s = enc_spk[gidx];
    float nm = __fadd_rn(__fadd_rn(__fmul_rn(__fmul_rn(m, 0.2f), __fsub_rn(1.f, s)), dot), encB[j]);
    enc_mem[gidx] = nm;
    float spk = nm > 0.5f ? 1.f : 0.f;
    enc_spk[gidx] = spk;
    sp[n * 129 + j] = spk;
  }
  __syncthreads();
  const int lane = tid & 63;
  const int w = tid >> 6;
  const float* spn = sp + lane * 129;
  if (w < 4) {
    const int ch0 = w * 16;
    const float* Wp = basesW + ch0;
    float acc[16];
    #pragma unroll
    for (int c = 0; c < 16; ++c) acc[c] = 0.f;
    for (int j = 0; j < 128; ++j) {
      const float s = spn[j];
      const float* wr = Wp + j * 64;
      #pragma unroll
      for (int c = 0; c < 16; ++c) acc[c] = __fmaf_rn(s, wr[c], acc[c]);
    }
    #pragma unroll
    for (int c = 0; c < 16; ++c) ob[lane * 65 + ch0 + c] = acc[c];
  } else {
    const int ch0 = (w - 4) * 8;
    const float* Wp = combW + ch0;
    float acc[8];
    #pragma unroll
    for (int c = 0; c < 8; ++c) acc[c] = 0.f;
    for (int j = 0; j < 128; ++j) {
      const float s = spn[j];
      const float* wr = Wp + j * 32;
      #pragma unroll
      for (int c = 0; c < 8; ++c) acc[c] = __fmaf_rn(s, wr[c], acc[c]);
    }
    #pragma unroll
    for (int c = 0; c < 8; ++c) oc[lane * 33 + ch0 + c] = acc[c];
  }
  __syncthreads();
  #pragma unroll
  for (int r = 0; r < 8; ++r) {
    int idx = r * 512 + tid;
    int n = idx >> 6, ch = idx & 63;
    bases[(size_t)(nb + n) * 64 + ch] = __fadd_rn(ob[n * 65 + ch], basesB[ch]);
  }
  #pragma unroll
  for (int r = 0; r < 4; ++r) {
    int idx = r * 512 + tid;
    int n = idx >> 5, ch = idx & 31;
    comb[(size_t)(nb + n) * 32 + ch] = __fadd_rn(oc[n * 33 + ch], combB[ch]);
  }
}

// fused: symnorm aggregation -> einsum -> conv LIF -> c1 spike (x4 unrolled gather)
__global__ __launch_bounds__(256) void k_aggconv(
    const float* __restrict__ bases, const float* __restrict__ comb,
    const float* __restrict__ dinv, const int* __restrict__ rowp,
    const int* __restrict__ col, const float* __restrict__ colw,
    const float* __restrict__ convB,
    float* __restrict__ c1_mem, float* __restrict__ c1_spk) {
  __shared__ float aggl[4][64];
  __shared__ float combl[4][32];
  int w = threadIdx.x >> 6;
  int m = threadIdx.x & 63;
  int d = blockIdx.x * 4 + w;
  float dd = dinv[d];
  int r0 = rowp[d], r1 = rowp[d + 1];
  float acc = 0.f;
  int r = r0;
  for (; r + 4 <= r1; r += 4) {
    const int s0 = col[r], s1 = col[r + 1], s2 = col[r + 2], s3 = col[r + 3];
    const float w0 = colw[r], w1 = colw[r + 1], w2 = colw[r + 2], w3 = colw[r + 3];
    const float b0 = bases[(size_t)s0 * 64 + m];
    const float b1 = bases[(size_t)s1 * 64 + m];
    const float b2 = bases[(size_t)s2 * 64 + m];
    const float b3 = bases[(size_t)s3 * 64 + m];
    acc = __fadd_rn(acc, __fmul_rn(__fmul_rn(w0, dd), b0));
    acc = __fadd_rn(acc, __fmul_rn(__fmul_rn(w1, dd), b1));
    acc = __fadd_rn(acc, __fmul_rn(__fmul_rn(w2, dd), b2));
    acc = __fadd_rn(acc, __fmul_rn(__fmul_rn(w3, dd), b3));
  }
  for (; r < r1; ++r) {
    int s = col[r];
    float ew  = __fmul_rn(colw[r], dd);
    float upd = __fmul_rn(ew, bases[(size_t)s * 64 + m]);
    acc = __fadd_rn(acc, upd);
  }
  {
    float ew  = __fmul_rn(dd, dd);
    float upd = __fmul_rn(ew, bases[(size_t)d * 64 + m]);
    acc = __fadd_rn(acc, upd);
  }
  aggl[w][m] = acc;
  if (m < 32) combl[w][m] = comb[(size_t)d * 32 + m];
  __syncthreads();
  #pragma unroll
  for (int half = 0; half < 2; ++half) {
    int j = m + half * 64;
    int h = j >> 4, f = j & 15;
    float cv = 0.f;
    #pragma unroll
    for (int b = 0; b < 4; ++b)
      cv = __fadd_rn(cv, __fmul_rn(combl[w][h * 4 + b], aggl[w][b * 16 + f]));
    cv = __fadd_rn(cv, convB[j]);
    int idx = d * 128 + j;
    float cm = c1_mem[idx], cs = c1_spk[idx];
    float nm = __fadd_rn(__fmul_rn(__fmul_rn(cm, 0.2f), __fsub_rn(1.f, cs)), cv);
    c1_mem[idx] = nm;
    c1_spk[idx] = nm > 0.5f ? 1.f : 0.f;
  }
}

// SPARSE row-wise gates, 4-way column-split: grid (4, 256); block q handles
// cols q*512..q*512+511 of graph s (one col per thread, coalesced scalar loads).
// Identical per-(s,col) chain to the R11-verified kernel: nonzero-k list in
// ascending order, fadds ascending k within panel, 22 left-to-right panel
// folds, dense lh@Whh per col ascending k, ((tih+bih)+(p22+p23))+bhh.
__global__ __launch_bounds__(512) void k_gates(
    const float* __restrict__ xl, const float* __restrict__ lh,
    const float* __restrict__ Wih, const float* __restrict__ Whh,
    const float* __restrict__ bih, const float* __restrict__ bhh,
    float* __restrict__ gates) {
  __shared__ unsigned short nzk[8192];
  __shared__ float lhs[512];
  __shared__ int wsum[9];
  const int tid = threadIdx.x;
  const int s = blockIdx.y;
  const int q = blockIdx.x;
  const int lane = tid & 63, wv = tid >> 6;
  const float* __restrict__ srow = xl + (size_t)s * 8192;

  // pass 1: count nonzeros in my 16-k chunk
  const int kb = tid * 16;
  int cnt = 0;
  #pragma unroll
  for (int i = 0; i < 16; ++i) cnt += (srow[kb + i] != 0.f) ? 1 : 0;
  // wave-inclusive prefix sum of counts
  int pfx = cnt;
  #pragma unroll
  for (int off = 1; off < 64; off <<= 1) {
    int tval = __shfl_up(pfx, off);
    if (lane >= off) pfx += tval;
  }
  if (lane == 63) wsum[wv] = pfx;
  __syncthreads();
  if (tid == 0) {
    int a = 0;
    #pragma unroll
    for (int w = 0; w < 8; ++w) { int tv = wsum[w]; wsum[w] = a; a += tv; }
    wsum[8] = a;
  }
  __syncthreads();
  const int off0 = wsum[wv] + (pfx - cnt);
  // pass 2: write ascending k-indices (no register-indexed arrays)
  {
    int c2 = 0;
    #pragma unroll
    for (int i = 0; i < 16; ++i) {
      if (srow[kb + i] != 0.f) { nzk[off0 + c2] = (unsigned short)(kb + i); ++c2; }
    }
  }
  lhs[tid] = lh[s * 512 + tid];
  __syncthreads();
  const int nnz = wsum[8];

  const int cl = q * 512 + tid;        // this thread's single output column
  const float* __restrict__ Wc = Wih + cl;
  float tih = 0.f;
  float pz  = 0.f;
  int zcur = 0, pend = 384;

#define FOLD(KK)                                                              \
  while ((KK) >= pend) {                                                      \
    tih = __fadd_rn(tih, pz); pz = 0.f;                                       \
    ++zcur; pend = (zcur < 21) ? (pend + 384) : 8192;                         \
  }

  // depth-8 pipeline (named scalar slots; compile-time indices only)
  int k0_=0,k1_=0,k2_=0,k3_=0,k4_=0,k5_=0,k6_=0,k7_=0;
  float w0_=0.f,w1_=0.f,w2_=0.f,w3_=0.f,w4_=0.f,w5_=0.f,w6_=0.f,w7_=0.f;
#define PRELOAD(J, KS, WS)                                                    \
  if ((J) < nnz) { KS = nzk[(J)]; WS = Wc[(size_t)KS * 2048]; }
  PRELOAD(0, k0_, w0_) PRELOAD(1, k1_, w1_) PRELOAD(2, k2_, w2_) PRELOAD(3, k3_, w3_)
  PRELOAD(4, k4_, w4_) PRELOAD(5, k5_, w5_) PRELOAD(6, k6_, w6_) PRELOAD(7, k7_, w7_)

#define STEP(KS, WS, BI, SO) {                                                \
    const int kcur = KS; const float wval = WS;                               \
    const int nidx = (BI) + (SO) + 8;                                         \
    if (nidx < nnz) { KS = nzk[nidx]; WS = Wc[(size_t)KS * 2048]; }           \
    FOLD(kcur);                                                               \
    pz = __fadd_rn(pz, wval);                                                 \
  }

  const int nmain = nnz & ~7;
  for (int i = 0; i < nmain; i += 8) {
    STEP(k0_, w0_, i, 0) STEP(k1_, w1_, i, 1) STEP(k2_, w2_, i, 2) STEP(k3_, w3_, i, 3)
    STEP(k4_, w4_, i, 4) STEP(k5_, w5_, i, 5) STEP(k6_, w6_, i, 6) STEP(k7_, w7_, i, 7)
  }
  for (int i = nmain; i < nnz; ++i) {
    const int kcur = nzk[i];
    const float wval = Wc[(size_t)kcur * 2048];
    FOLD(kcur);
    pz = __fadd_rn(pz, wval);
  }
  // fold remaining panels (first adds current pz, rest add +0) -> 22 folds total
  for (; zcur < 22; ++zcur) { tih = __fadd_rn(tih, pz); pz = 0.f; }
#undef STEP
#undef PRELOAD
#undef FOLD

  // dense lh @ Whh: panel 22 (k 0..383), panel 23 (k 384..511); thh = p22 + p23
  float p22 = 0.f;
  #pragma unroll 4
  for (int k = 0; k < 384; ++k)
    p22 = __fmaf_rn(lhs[k], Whh[(size_t)k * 2048 + cl], p22);
  float p23 = 0.f;
  #pragma unroll 4
  for (int k = 384; k < 512; ++k)
    p23 = __fmaf_rn(lhs[k], Whh[(size_t)k * 2048 + cl], p23);

  const float g = __fadd_rn(__fadd_rn(__fadd_rn(tih, bih[cl]), __fadd_rn(p22, p23)), bhh[cl]);
  gates[(size_t)s * 2048 + cl] = g;
}

// fused: gate spikes -> LSTM cell -> fc1 LIF -> fc2 LIF -> h2 accum. 512 threads.
__global__ __launch_bounds__(512) void k_cell(
    const float* __restrict__ gates,
    float* __restrict__ lc, float* __restrict__ lh,
    const float* __restrict__ fc1W, const float* __restrict__ fc1b,
    const float* __restrict__ fc2W, const float* __restrict__ fc2b,
    float* __restrict__ h1_mem, float* __restrict__ h1_spk,
    float* __restrict__ h2_mem, float* __restrict__ h2_spk, float* __restrict__ h2_sum) {
  __shared__ float lhl[512];
  __shared__ float a1buf[256];
  __shared__ float sp1l[256];
  const int s = blockIdx.x;
  const int tid = threadIdx.x;
  {
    const int h = tid;
    const float giv = gates[(size_t)s * 2048 + h];
    const float gfv = gates[(size_t)s * 2048 + 512 + h];
    const float ggv = gates[(size_t)s * 2048 + 1024 + h];
    const float gov = gates[(size_t)s * 2048 + 1536 + h];
    const float iv = giv > 0.f ? 1.f : 0.f;
    const float fv = gfv > 0.f ? 1.f : 0.f;
    const float gv = ggv > 0.f ? 1.f : 0.f;
    const float ov = gov > 0.f ? 1.f : 0.f;
    const int li = s * 512 + h;
    const float lcv = __fadd_rn(__fmul_rn(fv, lc[li]), __fmul_rn(iv, gv));
    lc[li] = lcv;
    const float lhv = __fmul_rn(lcv, ov);
    lh[li] = lhv;
    lhl[h] = lhv;
  }
  __syncthreads();
  float a0 = 0.f;
  if (tid < 256) {
    const int p = tid;
    #pragma unroll 8
    for (int q = 0; q < 384; ++q) a0 = __fmaf_rn(lhl[q], fc1W[q * 256 + p], a0);
  } else {
    const int p = tid - 256;
    float a1 = 0.f;
    #pragma unroll 8
    for (int q = 384; q < 512; ++q) a1 = __fmaf_rn(lhl[q], fc1W[q * 256 + p], a1);
    a1buf[p] = a1;
  }
  __syncthreads();
  if (tid < 256) {
    const int p = tid;
    const float dot1 = __fadd_rn(a0, a1buf[p]);
    const int i1 = s * 256 + p;
    const float m1 = h1_mem[i1], s1o = h1_spk[i1];
    const float nm1 = __fadd_rn(__fadd_rn(__fmul_rn(__fmul_rn(m1, 0.2f), __fsub_rn(1.f, s1o)), dot1), fc1b[p]);
    h1_mem[i1] = nm1;
    const float sp1 = nm1 > 0.5f ? 1.f : 0.f;
    h1_spk[i1] = sp1;
    sp1l[p] = sp1;
  }
  __syncthreads();
  if (tid < 4) {
    const int p = tid;
    float acc = 0.f;
    for (int q = 0; q < 256; ++q) acc = __fmaf_rn(sp1l[q], fc2W[q * 4 + p], acc);
    const int i2 = s * 4 + p;
    const float m2 = h2_mem[i2], s2o = h2_spk[i2];
    const float nm2 = __fadd_rn(__fadd_rn(__fmul_rn(__fmul_rn(m2, 0.2f), __fsub_rn(1.f, s2o)), acc), fc2b[p]);
    h2_mem[i2] = nm2;
    const float sp2 = nm2 > 0.5f ? 1.f : 0.f;
    h2_spk[i2] = sp2;
    h2_sum[i2] = __fadd_rn(h2_sum[i2], sp2);
  }
}

__global__ void k_out(const float* __restrict__ h2_sum, float* __restrict__ out) {
  int i = blockIdx.x * 256 + threadIdx.x;
  if (i < SG * 4) out[i] = __fmul_rn(h2_sum[i], 0.03125f);
}

// ---------------- launch ----------------
extern "C" void kernel_launch(void* const* d_in, const int* in_sizes, int n_in,
                              void* d_out, int out_size, void* d_ws, size_t ws_size,
                              hipStream_t stream) {
  const float* x      = (const float*)d_in[0];
  const int*   ei     = (const int*)  d_in[1];
  const float* encW   = (const float*)d_in[2];
  const float* encB   = (const float*)d_in[3];
  const float* basesW = (const float*)d_in[4];
  const float* basesB = (const float*)d_in[5];
  const float* combW  = (const float*)d_in[6];
  const float* combB  = (const float*)d_in[7];
  const float* convB  = (const float*)d_in[8];
  const float* Wih    = (const float*)d_in[9];
  const float* Whh    = (const float*)d_in[10];
  const float* bih    = (const float*)d_in[11];
  const float* bhh    = (const float*)d_in[12];
  const float* fc1W   = (const float*)d_in[13];
  const float* fc1b   = (const float*)d_in[14];
  const float* fc2W   = (const float*)d_in[15];
  const float* fc2b   = (const float*)d_in[16];

  float* ws = (float*)d_ws;
  float* enc_mem = ws + OFF_ENC_MEM;
  float* enc_spk = ws + OFF_ENC_SPK;
  float* c1_mem  = ws + OFF_C1_MEM;
  float* c1_spk  = ws + OFF_C1_SPK;   // xl
  float* lhp     = ws + OFF_LH;
  float* lcp     = ws + OFF_LC;
  float* h1_mem  = ws + OFF_H1_MEM;
  float* h1_spk  = ws + OFF_H1_SPK;
  float* h2_mem  = ws + OFF_H2_MEM;
  float* h2_spk  = ws + OFF_H2_SPK;
  float* h2_sum  = ws + OFF_H2_SUM;
  float* bases   = ws + OFF_BASES;
  float* comb    = ws + OFF_COMB;
  float* gates   = ws + OFF_GATES;
  float* dinv    = ws + OFF_DINV;
  float* colw    = ws + OFF_COLW;
  int* ibase = (int*)((char*)d_ws + (size_t)FLOAT_END * 4);
  int* deg  = ibase + IOFF_DEG;
  int* fill = ibase + IOFF_FILL;
  int* rowp = ibase + IOFF_ROWPTR;
  int* eid  = ibase + IOFF_EID;
  int* col  = ibase + IOFF_COL;

  hipMemsetAsync(ws, 0, (size_t)ZERO_FLOATS * 4, stream);
  hipMemsetAsync(ibase, 0, 32768 * 4, stream);

  k_deg    <<<NE / 256, 256, 0, stream>>>(ei, deg);
  k_dinv   <<<NN / 256, 256, 0, stream>>>(deg, dinv);
  k_scan   <<<1, 1024, 0, stream>>>(deg, rowp);
  k_scatter<<<NE / 256, 256, 0, stream>>>(ei, rowp, fill, eid);
  k_sortadj<<<NN / 256, 256, 0, stream>>>(rowp, eid, ei, dinv, col, colw);

  for (int t = 0; t < TSTEPS; ++t) {
    k_bases_comb<<<NN / 64, 512, 0, stream>>>(x, encW, encB, enc_mem, enc_spk,
                                              basesW, basesB, combW, combB, bases, comb, t);
    k_aggconv   <<<NN / 4, 256, 0, stream>>>(bases, comb, dinv, rowp, col, colw, convB, c1_mem, c1_spk);
    k_gates     <<<dim3(4, SG), 512, 0, stream>>>(c1_spk, lhp, Wih, Whh, bih, bhh, gates);
    k_cell      <<<SG, 512, 0, stream>>>(gates, lcp, lhp, fc1W, fc1b, fc2W, fc2b,
                                         h1_mem, h1_spk, h2_mem, h2_spk, h2_sum);
  }
  k_out<<<4, 256, 0, stream>>>(h2_sum, (float*)d_out);
}